// Round 5
// baseline (205.023 us; speedup 1.0000x reference)
//
#include <hip/hip_runtime.h>

// Problem constants: B=16384, D_in=512, H=512
#define M_ROWS 16384
#define N_COLS 1536   // 3*H
#define K_DIM  512
#define H_DIM  512

typedef __attribute__((ext_vector_type(8))) short short8;   // 8 bf16 = 4 VGPRs
typedef __attribute__((ext_vector_type(16))) float f32x16;  // 32x32 MFMA acc

__device__ __forceinline__ unsigned short f2bf(float f) {
  unsigned u = __float_as_uint(f);
  u += 0x7fffu + ((u >> 16) & 1u);   // RNE
  return (unsigned short)(u >> 16);
}
__device__ __forceinline__ float bf2f(unsigned short h) {
  return __uint_as_float(((unsigned)h) << 16);
}

__device__ __forceinline__ void gload_lds16(const void* g, void* l) {
  __builtin_amdgcn_global_load_lds((const __attribute__((address_space(1))) void*)g,
                                   (__attribute__((address_space(3))) void*)l,
                                   16, 0, 0);
}

// ---------------- fp32 -> bf16 convert, grid-stride (10 float4 / thread) ----
// unified f4 index space: x [0,2097152) | hx [.., 4194304) | Wi [..,4390912) | Wh [..,4587520)
__global__ __launch_bounds__(256) void cvt_all(
    const float* __restrict__ x, const float* __restrict__ hx,
    const float* __restrict__ Wi, const float* __restrict__ Wh,
    unsigned short* __restrict__ xb, unsigned short* __restrict__ hxb,
    unsigned short* __restrict__ Wib, unsigned short* __restrict__ Whb) {
  const int stride = 1792 * 256;           // grid exactly 1792 blocks x 256
  int i = blockIdx.x * 256 + threadIdx.x;
#pragma unroll
  for (int it = 0; it < 10; ++it, i += stride) {
    const float* s; unsigned short* d; int off;
    if (i < 2097152)      { s = x;  d = xb;  off = i; }
    else if (i < 4194304) { s = hx; d = hxb; off = i - 2097152; }
    else if (i < 4390912) { s = Wi; d = Wib; off = i - 4194304; }
    else                  { s = Wh; d = Whb; off = i - 4390912; }
    float4 f = ((const float4*)s)[off];
    ushort4 u;
    u.x = f2bf(f.x); u.y = f2bf(f.y); u.z = f2bf(f.z); u.w = f2bf(f.w);
    ((ushort4*)d)[off] = u;
  }
}

// ---------------- GEMM (bf16 MFMA 32x32x16) + bias, permuted store ----------
// C[m][n] = sum_k A[m][k]*W[n][k] + bias[n].  blockIdx.z: 0=(x,Wi,bi,xt) 1=(hx,Wh,bh,ht)
// Tile BM=BN=128, BK=64; 4 waves 2x2; wave does 64x64 via 2x2 of 32x32x16 MFMA.
// LDS XOR swizzle: 16B chunk c of row r stored at physical chunk c^(r&7).
// Store permutation within each aligned 64-col group: value for true col
// 32*j + c (c=lane&31, j=0..1) stored at slot 2c+j, i.e. true = 32*(s&1)+(s>>1).
// NOTE: at 60.5us this is ~851 TF, within ~6% of the m97-structure plateau;
// kept byte-identical to round 4 (proven).
__global__ __launch_bounds__(256, 4) void gemm_bf16(
    const unsigned short* __restrict__ xb, const unsigned short* __restrict__ hxb,
    const unsigned short* __restrict__ Wib, const unsigned short* __restrict__ Whb,
    const float* __restrict__ b_i2h, const float* __restrict__ b_h2h,
    unsigned short* __restrict__ xt, unsigned short* __restrict__ ht) {
  const int mat = blockIdx.z;
  const unsigned short* A  = mat ? hxb : xb;
  const unsigned short* Bw = mat ? Whb : Wib;
  const float* bias        = mat ? b_h2h : b_i2h;
  unsigned short* outp     = mat ? ht : xt;

  const int m0 = blockIdx.x * 128;
  const int n0 = blockIdx.y * 128;

  __shared__ short lds[2 * 128 * 64];  // A tile then B tile, 32 KiB
  short* ldsA = lds;
  short* ldsB = lds + 128 * 64;

  const int t = threadIdx.x;
  const int w = t >> 6, lane = t & 63;
  const int w_row = w >> 1, w_col = w & 1;
  const int l31 = lane & 31, h = lane >> 5;

  f32x16 acc[2][2];
#pragma unroll
  for (int i = 0; i < 2; ++i)
#pragma unroll
    for (int j = 0; j < 2; ++j)
#pragma unroll
      for (int r = 0; r < 16; ++r) acc[i][j][r] = 0.f;

  const int srow = lane >> 3;                       // 0..7 row within 8-row seg
  const int scol = ((lane & 7) ^ srow) * 8;         // XOR-swizzled source chunk

  for (int k0 = 0; k0 < K_DIM; k0 += 64) {
#pragma unroll
    for (int q = 0; q < 4; ++q) {
      const int base_row = w * 32 + q * 8;
      gload_lds16(A  + (size_t)(m0 + base_row + srow) * K_DIM + k0 + scol,
                  &ldsA[base_row * 64]);
      gload_lds16(Bw + (size_t)(n0 + base_row + srow) * K_DIM + k0 + scol,
                  &ldsB[base_row * 64]);
    }
    __syncthreads();
#pragma unroll
    for (int kk = 0; kk < 4; ++kk) {
      // lane needs A[m=l31][k = kk*16 + h*8 + j] -> logical chunk kk*2+h,
      // physical chunk (kk*2+h) ^ (l31&7)
      const int chunk = ((kk * 2 + h) ^ (l31 & 7)) * 8;
      short8 af[2], bf[2];
#pragma unroll
      for (int i = 0; i < 2; ++i)
        af[i] = *(const short8*)&ldsA[(w_row * 64 + i * 32 + l31) * 64 + chunk];
#pragma unroll
      for (int j = 0; j < 2; ++j)
        bf[j] = *(const short8*)&ldsB[(w_col * 64 + j * 32 + l31) * 64 + chunk];
#pragma unroll
      for (int i = 0; i < 2; ++i)
#pragma unroll
        for (int j = 0; j < 2; ++j)
          acc[i][j] = __builtin_amdgcn_mfma_f32_32x32x16_bf16(af[i], bf[j], acc[i][j], 0, 0, 0);
    }
    __syncthreads();
  }

  // Epilogue: bias + packed permuted ushort2 store.
  // C/D: col=l31, row=(reg&3)+8*(reg>>2)+4*h
  const float biasj0 = bias[n0 + w_col * 64 + l31];
  const float biasj1 = bias[n0 + w_col * 64 + 32 + l31];

#pragma unroll
  for (int i = 0; i < 2; ++i) {
#pragma unroll
    for (int g = 0; g < 4; ++g) {
#pragma unroll
      for (int d = 0; d < 4; ++d) {
        const int reg = g * 4 + d;
        const int row = d + 8 * g + 4 * h;
        ushort2 pk;
        pk.x = f2bf(acc[i][0][reg] + biasj0);
        pk.y = f2bf(acc[i][1][reg] + biasj1);
        *(ushort2*)(outp + (size_t)(m0 + w_row * 64 + i * 32 + row) * N_COLS +
                    n0 + w_col * 64 + 2 * l31) = pk;
      }
    }
  }
}

// ---------------- finalize: wave-per-row, b128 loads, cheap reduction -------
// Permuted slot s (within aligned 64-group) holds true col 32*(s&1)+(s>>1).
// Lane l reads slots 8l..8l+7: true cols 64*(l>>3) + 32*(e&1) + 4*(l&7) + (e>>1).
// Stats: 8 channels reduced with a channel-halving butterfly (10 shfls total
// instead of 48), published through LDS.
__global__ __launch_bounds__(256) void finalize_kernel(
    const unsigned short* __restrict__ xt, const unsigned short* __restrict__ ht,
    const unsigned short* __restrict__ hxb, float* __restrict__ out) {
  const int w = threadIdx.x >> 6, lane = threadIdx.x & 63;
  const int b = blockIdx.x * 4 + w;            // one row per wave
  const size_t rb = (size_t)b * N_COLS;

  short8 sxr = *(const short8*)&xt[rb + 8 * lane];
  short8 sxz = *(const short8*)&xt[rb + 512 + 8 * lane];
  short8 sxn = *(const short8*)&xt[rb + 1024 + 8 * lane];
  short8 shr = *(const short8*)&ht[rb + 8 * lane];
  short8 shz = *(const short8*)&ht[rb + 512 + 8 * lane];
  short8 shn = *(const short8*)&ht[rb + 1024 + 8 * lane];

  float vxr[8], vxz[8], vxn[8], vhr[8], vhz[8], vhn[8];
#pragma unroll
  for (int k = 0; k < 8; ++k) {
    vxr[k] = bf2f((unsigned short)sxr[k]);
    vxz[k] = bf2f((unsigned short)sxz[k]);
    vxn[k] = bf2f((unsigned short)sxn[k]);
    vhr[k] = bf2f((unsigned short)shr[k]);
    vhz[k] = bf2f((unsigned short)shz[k]);
    vhn[k] = bf2f((unsigned short)shn[k]);
  }

  float pr[8] = {0.f, 0.f, 0.f, 0.f, 0.f, 0.f, 0.f, 0.f};
#pragma unroll
  for (int k = 0; k < 8; ++k) {
    pr[0] += vxr[k] + vxz[k];
    pr[1] += vxr[k] * vxr[k] + vxz[k] * vxz[k];
    pr[2] += vxn[k];
    pr[3] += vxn[k] * vxn[k];
    pr[4] += vhr[k] + vhz[k];
    pr[5] += vhr[k] * vhr[k] + vhz[k] * vhz[k];
    pr[6] += vhn[k];
    pr[7] += vhn[k] * vhn[k];
  }

  // channel-halving butterfly: send what you don't keep, add what you receive
  const bool b0 = lane & 1, b1 = lane & 2, b2 = lane & 4;
#pragma unroll
  for (int k = 0; k < 4; ++k) {               // xor 1: 8 ch -> 4 ch
    float send = b0 ? pr[k] : pr[k + 4];
    float keep = b0 ? pr[k + 4] : pr[k];
    pr[k] = keep + __shfl_xor(send, 1);
  }
#pragma unroll
  for (int k = 0; k < 2; ++k) {               // xor 2: 4 ch -> 2 ch
    float send = b1 ? pr[k] : pr[k + 2];
    float keep = b1 ? pr[k + 2] : pr[k];
    pr[k] = keep + __shfl_xor(send, 2);
  }
  {                                           // xor 4: 2 ch -> 1 ch
    float send = b2 ? pr[0] : pr[1];
    float keep = b2 ? pr[1] : pr[0];
    pr[0] = keep + __shfl_xor(send, 4);
  }
  float tot = pr[0];
  tot += __shfl_xor(tot, 8);
  tot += __shfl_xor(tot, 16);
  tot += __shfl_xor(tot, 32);
  // lane holds channel c = 4*(lane&1) + 2*((lane>>1)&1) + ((lane>>2)&1), full sum

  __shared__ float sst[4][8];
  if (lane < 8) {
    const int c = ((lane & 1) << 2) | (lane & 2) | ((lane >> 2) & 1);
    sst[w][c] = tot;
  }
  __syncthreads();

  const float inv2H = 1.f / 1024.f, invH = 1.f / 512.f;
  const float mx0 = sst[w][0] * inv2H;
  const float ix0 = rsqrtf(sst[w][1] * inv2H - mx0 * mx0 + 1e-5f);
  const float mx1 = sst[w][2] * invH;
  const float ix1 = rsqrtf(sst[w][3] * invH - mx1 * mx1 + 1e-5f);
  const float mh0 = sst[w][4] * inv2H;
  const float ih0 = rsqrtf(sst[w][5] * inv2H - mh0 * mh0 + 1e-5f);
  const float mh1 = sst[w][6] * invH;
  const float ih1 = rsqrtf(sst[w][7] * invH - mh1 * mh1 + 1e-5f);

  auto calc = [&](float xrv, float xzv, float xnv, float hrv, float hzv,
                  float hnv, float hxs) -> float {
    float ar = (xrv - mx0) * ix0 + (hrv - mh0) * ih0;
    float az = (xzv - mx0) * ix0 + (hzv - mh0) * ih0;
    float r = 1.f / (1.f + __expf(-ar));
    float z = 1.f / (1.f + __expf(-az));
    float arg = (xnv - mx1) * ix1 + r * ((hnv - mh1) * ih1);
    float e2 = __expf(2.f * arg);
    float nn = (e2 - 1.f) / (e2 + 1.f);
    return z * hxs + (1.f - z) * nn;
  };

  const int base4 = 64 * (lane >> 3) + 4 * (lane & 7);
  const unsigned short* hxrow = hxb + (size_t)b * H_DIM;
  float* orow = out + (size_t)b * H_DIM;

  ushort4 hx0u = *(const ushort4*)&hxrow[base4];
  ushort4 hx1u = *(const ushort4*)&hxrow[base4 + 32];
  float hx0[4] = {bf2f(hx0u.x), bf2f(hx0u.y), bf2f(hx0u.z), bf2f(hx0u.w)};
  float hx1[4] = {bf2f(hx1u.x), bf2f(hx1u.y), bf2f(hx1u.z), bf2f(hx1u.w)};

  float4 r0, r1;
  float* r0p = (float*)&r0;
  float* r1p = (float*)&r1;
#pragma unroll
  for (int k = 0; k < 4; ++k) {
    r0p[k] = calc(vxr[2 * k], vxz[2 * k], vxn[2 * k],
                  vhr[2 * k], vhz[2 * k], vhn[2 * k], hx0[k]);
    r1p[k] = calc(vxr[2 * k + 1], vxz[2 * k + 1], vxn[2 * k + 1],
                  vhr[2 * k + 1], vhz[2 * k + 1], vhn[2 * k + 1], hx1[k]);
  }
  *(float4*)&orow[base4] = r0;
  *(float4*)&orow[base4 + 32] = r1;
}

// ---------------- launch ----------------
// Workspace layout (bytes):            offset        size
//   xb  (bf16 x,  16384x512)               0      16777216
//   hxb (bf16 hx, 16384x512)        16777216      16777216
//   Wib (bf16,  1536x512)           33554432       1572864
//   Whb (bf16,  1536x512)           35127296       1572864
//   xt  (bf16, 16384x1536, permuted) 36700160     50331648
//   ht  (bf16, 16384x1536, permuted) 87031808     50331648
extern "C" void kernel_launch(void* const* d_in, const int* in_sizes, int n_in,
                              void* d_out, int out_size, void* d_ws, size_t ws_size,
                              hipStream_t stream) {
  const float* x  = (const float*)d_in[0];
  const float* hx = (const float*)d_in[1];
  const float* Wi = (const float*)d_in[2];
  const float* bi = (const float*)d_in[3];
  const float* Wh = (const float*)d_in[4];
  const float* bh = (const float*)d_in[5];
  float* out = (float*)d_out;

  char* ws = (char*)d_ws;
  unsigned short* xb  = (unsigned short*)(ws);
  unsigned short* hxb = (unsigned short*)(ws + 16777216);
  unsigned short* Wib = (unsigned short*)(ws + 33554432);
  unsigned short* Whb = (unsigned short*)(ws + 35127296);
  unsigned short* xt  = (unsigned short*)(ws + 36700160);
  unsigned short* ht  = (unsigned short*)(ws + 87031808);

  cvt_all<<<1792, 256, 0, stream>>>(x, hx, Wi, Wh, xb, hxb, Wib, Whb);

  gemm_bf16<<<dim3(M_ROWS / 128, N_COLS / 128, 2), 256, 0, stream>>>(
      xb, hxb, Wib, Whb, bi, bh, xt, ht);

  finalize_kernel<<<M_ROWS / 4, 256, 0, stream>>>(xt, ht, hxb, out);
}

// Round 6
// 202.676 us; speedup vs baseline: 1.0116x; 1.0116x over previous
//
#include <hip/hip_runtime.h>

// Problem constants: B=16384, D_in=512, H=512
#define M_ROWS 16384
#define N_COLS 1536   // 3*H
#define K_DIM  512
#define H_DIM  512

typedef __attribute__((ext_vector_type(8))) short short8;   // 8 bf16 = 4 VGPRs
typedef __attribute__((ext_vector_type(16))) float f32x16;  // 32x32 MFMA acc

__device__ __forceinline__ unsigned short f2bf(float f) {
  unsigned u = __float_as_uint(f);
  u += 0x7fffu + ((u >> 16) & 1u);   // RNE
  return (unsigned short)(u >> 16);
}
__device__ __forceinline__ float bf2f(unsigned short h) {
  return __uint_as_float(((unsigned)h) << 16);
}

__device__ __forceinline__ void gload_lds16(const void* g, void* l) {
  __builtin_amdgcn_global_load_lds((const __attribute__((address_space(1))) void*)g,
                                   (__attribute__((address_space(3))) void*)l,
                                   16, 0, 0);
}

// ---------------- fp32 -> bf16 convert, grid-stride (10 float4 / thread) ----
// unified f4 index space: x [0,2097152) | hx [.., 4194304) | Wi [..,4390912) | Wh [..,4587520)
__global__ __launch_bounds__(256) void cvt_all(
    const float* __restrict__ x, const float* __restrict__ hx,
    const float* __restrict__ Wi, const float* __restrict__ Wh,
    unsigned short* __restrict__ xb, unsigned short* __restrict__ hxb,
    unsigned short* __restrict__ Wib, unsigned short* __restrict__ Whb) {
  const int stride = 1792 * 256;           // grid exactly 1792 blocks x 256
  int i = blockIdx.x * 256 + threadIdx.x;
#pragma unroll
  for (int it = 0; it < 10; ++it, i += stride) {
    const float* s; unsigned short* d; int off;
    if (i < 2097152)      { s = x;  d = xb;  off = i; }
    else if (i < 4194304) { s = hx; d = hxb; off = i - 2097152; }
    else if (i < 4390912) { s = Wi; d = Wib; off = i - 4194304; }
    else                  { s = Wh; d = Whb; off = i - 4390912; }
    float4 f = ((const float4*)s)[off];
    ushort4 u;
    u.x = f2bf(f.x); u.y = f2bf(f.y); u.z = f2bf(f.z); u.w = f2bf(f.w);
    ((ushort4*)d)[off] = u;
  }
}

// ---------------- GEMM (bf16 MFMA 32x32x16) + bias, permuted store ----------
// C[m][n] = sum_k A[m][k]*W[n][k] + bias[n].  blockIdx.z: 0=(x,Wi,bi,xt) 1=(hx,Wh,bh,ht)
// Tile BM=256, BN=128, BK=64; 4 waves 2x2; wave tile 128x64 via 4x2 of
// 32x32x16 MFMA -> 6 ds_read_b128 per 8 MFMA (0.75 reads/MFMA vs 1.0 at 64x64).
// LDS XOR swizzle: 16B chunk c of row r stored at physical chunk c^(r&7).
// Store permutation within each aligned 64-col group: value for true col
// 32*j + c (c=lane&31, j=0..1) stored at slot 2c+j, i.e. true = 32*(s&1)+(s>>1).
__global__ __launch_bounds__(256, 2) void gemm_bf16(
    const unsigned short* __restrict__ xb, const unsigned short* __restrict__ hxb,
    const unsigned short* __restrict__ Wib, const unsigned short* __restrict__ Whb,
    const float* __restrict__ b_i2h, const float* __restrict__ b_h2h,
    unsigned short* __restrict__ xt, unsigned short* __restrict__ ht) {
  const int mat = blockIdx.z;
  const unsigned short* A  = mat ? hxb : xb;
  const unsigned short* Bw = mat ? Whb : Wib;
  const float* bias        = mat ? b_h2h : b_i2h;
  unsigned short* outp     = mat ? ht : xt;

  const int m0 = blockIdx.x * 256;
  const int n0 = blockIdx.y * 128;

  __shared__ short lds[(256 + 128) * 64];  // A tile (32 KiB) then B tile (16 KiB)
  short* ldsA = lds;
  short* ldsB = lds + 256 * 64;

  const int t = threadIdx.x;
  const int w = t >> 6, lane = t & 63;
  const int w_row = w >> 1, w_col = w & 1;
  const int l31 = lane & 31, h = lane >> 5;

  f32x16 acc[4][2];
#pragma unroll
  for (int i = 0; i < 4; ++i)
#pragma unroll
    for (int j = 0; j < 2; ++j)
#pragma unroll
      for (int r = 0; r < 16; ++r) acc[i][j][r] = 0.f;

  const int srow = lane >> 3;                       // 0..7 row within 8-row seg
  const int scol = ((lane & 7) ^ srow) * 8;         // XOR-swizzled source chunk

  for (int k0 = 0; k0 < K_DIM; k0 += 64) {
    // A: 256 rows, each wave stages 64 rows (8 segments of 8)
#pragma unroll
    for (int q = 0; q < 8; ++q) {
      const int base_row = w * 64 + q * 8;
      gload_lds16(A + (size_t)(m0 + base_row + srow) * K_DIM + k0 + scol,
                  &ldsA[base_row * 64]);
    }
    // B: 128 rows, each wave stages 32 rows (4 segments of 8)
#pragma unroll
    for (int q = 0; q < 4; ++q) {
      const int base_row = w * 32 + q * 8;
      gload_lds16(Bw + (size_t)(n0 + base_row + srow) * K_DIM + k0 + scol,
                  &ldsB[base_row * 64]);
    }
    __syncthreads();
#pragma unroll
    for (int kk = 0; kk < 4; ++kk) {
      // lane needs A[m=l31][k = kk*16 + h*8 + j] -> logical chunk kk*2+h,
      // physical chunk (kk*2+h) ^ (l31&7)
      const int chunk = ((kk * 2 + h) ^ (l31 & 7)) * 8;
      short8 af[4], bf[2];
#pragma unroll
      for (int i = 0; i < 4; ++i)
        af[i] = *(const short8*)&ldsA[(w_row * 128 + i * 32 + l31) * 64 + chunk];
#pragma unroll
      for (int j = 0; j < 2; ++j)
        bf[j] = *(const short8*)&ldsB[(w_col * 64 + j * 32 + l31) * 64 + chunk];
#pragma unroll
      for (int i = 0; i < 4; ++i)
#pragma unroll
        for (int j = 0; j < 2; ++j)
          acc[i][j] = __builtin_amdgcn_mfma_f32_32x32x16_bf16(af[i], bf[j], acc[i][j], 0, 0, 0);
    }
    __syncthreads();
  }

  // Epilogue: bias + packed permuted ushort2 store.
  // C/D: col=l31, row=(reg&3)+8*(reg>>2)+4*h
  const float biasj0 = bias[n0 + w_col * 64 + l31];
  const float biasj1 = bias[n0 + w_col * 64 + 32 + l31];

#pragma unroll
  for (int i = 0; i < 4; ++i) {
#pragma unroll
    for (int g = 0; g < 4; ++g) {
#pragma unroll
      for (int d = 0; d < 4; ++d) {
        const int reg = g * 4 + d;
        const int row = d + 8 * g + 4 * h;
        ushort2 pk;
        pk.x = f2bf(acc[i][0][reg] + biasj0);
        pk.y = f2bf(acc[i][1][reg] + biasj1);
        *(ushort2*)(outp + (size_t)(m0 + w_row * 128 + i * 32 + row) * N_COLS +
                    n0 + w_col * 64 + 2 * l31) = pk;
      }
    }
  }
}

// ---------------- finalize: wave-per-row, b128 loads, cheap reduction -------
// Permuted slot s (within aligned 64-group) holds true col 32*(s&1)+(s>>1).
// Lane l reads slots 8l..8l+7: true cols 64*(l>>3) + 32*(e&1) + 4*(l&7) + (e>>1).
__global__ __launch_bounds__(256) void finalize_kernel(
    const unsigned short* __restrict__ xt, const unsigned short* __restrict__ ht,
    const unsigned short* __restrict__ hxb, float* __restrict__ out) {
  const int w = threadIdx.x >> 6, lane = threadIdx.x & 63;
  const int b = blockIdx.x * 4 + w;            // one row per wave
  const size_t rb = (size_t)b * N_COLS;

  short8 sxr = *(const short8*)&xt[rb + 8 * lane];
  short8 sxz = *(const short8*)&xt[rb + 512 + 8 * lane];
  short8 sxn = *(const short8*)&xt[rb + 1024 + 8 * lane];
  short8 shr = *(const short8*)&ht[rb + 8 * lane];
  short8 shz = *(const short8*)&ht[rb + 512 + 8 * lane];
  short8 shn = *(const short8*)&ht[rb + 1024 + 8 * lane];

  float vxr[8], vxz[8], vxn[8], vhr[8], vhz[8], vhn[8];
#pragma unroll
  for (int k = 0; k < 8; ++k) {
    vxr[k] = bf2f((unsigned short)sxr[k]);
    vxz[k] = bf2f((unsigned short)sxz[k]);
    vxn[k] = bf2f((unsigned short)sxn[k]);
    vhr[k] = bf2f((unsigned short)shr[k]);
    vhz[k] = bf2f((unsigned short)shz[k]);
    vhn[k] = bf2f((unsigned short)shn[k]);
  }

  float pr[8] = {0.f, 0.f, 0.f, 0.f, 0.f, 0.f, 0.f, 0.f};
#pragma unroll
  for (int k = 0; k < 8; ++k) {
    pr[0] += vxr[k] + vxz[k];
    pr[1] += vxr[k] * vxr[k] + vxz[k] * vxz[k];
    pr[2] += vxn[k];
    pr[3] += vxn[k] * vxn[k];
    pr[4] += vhr[k] + vhz[k];
    pr[5] += vhr[k] * vhr[k] + vhz[k] * vhz[k];
    pr[6] += vhn[k];
    pr[7] += vhn[k] * vhn[k];
  }

  // channel-halving butterfly: send what you don't keep, add what you receive
  const bool b0 = lane & 1, b1 = lane & 2, b2 = lane & 4;
#pragma unroll
  for (int k = 0; k < 4; ++k) {               // xor 1: 8 ch -> 4 ch
    float send = b0 ? pr[k] : pr[k + 4];
    float keep = b0 ? pr[k + 4] : pr[k];
    pr[k] = keep + __shfl_xor(send, 1);
  }
#pragma unroll
  for (int k = 0; k < 2; ++k) {               // xor 2: 4 ch -> 2 ch
    float send = b1 ? pr[k] : pr[k + 2];
    float keep = b1 ? pr[k + 2] : pr[k];
    pr[k] = keep + __shfl_xor(send, 2);
  }
  {                                           // xor 4: 2 ch -> 1 ch
    float send = b2 ? pr[0] : pr[1];
    float keep = b2 ? pr[1] : pr[0];
    pr[0] = keep + __shfl_xor(send, 4);
  }
  float tot = pr[0];
  tot += __shfl_xor(tot, 8);
  tot += __shfl_xor(tot, 16);
  tot += __shfl_xor(tot, 32);
  // lane holds channel c = 4*(lane&1) + 2*((lane>>1)&1) + ((lane>>2)&1), full sum

  __shared__ float sst[4][8];
  if (lane < 8) {
    const int c = ((lane & 1) << 2) | (lane & 2) | ((lane >> 2) & 1);
    sst[w][c] = tot;
  }
  __syncthreads();

  const float inv2H = 1.f / 1024.f, invH = 1.f / 512.f;
  const float mx0 = sst[w][0] * inv2H;
  const float ix0 = rsqrtf(sst[w][1] * inv2H - mx0 * mx0 + 1e-5f);
  const float mx1 = sst[w][2] * invH;
  const float ix1 = rsqrtf(sst[w][3] * invH - mx1 * mx1 + 1e-5f);
  const float mh0 = sst[w][4] * inv2H;
  const float ih0 = rsqrtf(sst[w][5] * inv2H - mh0 * mh0 + 1e-5f);
  const float mh1 = sst[w][6] * invH;
  const float ih1 = rsqrtf(sst[w][7] * invH - mh1 * mh1 + 1e-5f);

  auto calc = [&](float xrv, float xzv, float xnv, float hrv, float hzv,
                  float hnv, float hxs) -> float {
    float ar = (xrv - mx0) * ix0 + (hrv - mh0) * ih0;
    float az = (xzv - mx0) * ix0 + (hzv - mh0) * ih0;
    float r = 1.f / (1.f + __expf(-ar));
    float z = 1.f / (1.f + __expf(-az));
    float arg = (xnv - mx1) * ix1 + r * ((hnv - mh1) * ih1);
    float e2 = __expf(2.f * arg);
    float nn = (e2 - 1.f) / (e2 + 1.f);
    return z * hxs + (1.f - z) * nn;
  };

  const int base4 = 64 * (lane >> 3) + 4 * (lane & 7);
  const unsigned short* hxrow = hxb + (size_t)b * H_DIM;
  float* orow = out + (size_t)b * H_DIM;

  ushort4 hx0u = *(const ushort4*)&hxrow[base4];
  ushort4 hx1u = *(const ushort4*)&hxrow[base4 + 32];
  float hx0[4] = {bf2f(hx0u.x), bf2f(hx0u.y), bf2f(hx0u.z), bf2f(hx0u.w)};
  float hx1[4] = {bf2f(hx1u.x), bf2f(hx1u.y), bf2f(hx1u.z), bf2f(hx1u.w)};

  float4 r0, r1;
  float* r0p = (float*)&r0;
  float* r1p = (float*)&r1;
#pragma unroll
  for (int k = 0; k < 4; ++k) {
    r0p[k] = calc(vxr[2 * k], vxz[2 * k], vxn[2 * k],
                  vhr[2 * k], vhz[2 * k], vhn[2 * k], hx0[k]);
    r1p[k] = calc(vxr[2 * k + 1], vxz[2 * k + 1], vxn[2 * k + 1],
                  vhr[2 * k + 1], vhz[2 * k + 1], vhn[2 * k + 1], hx1[k]);
  }
  *(float4*)&orow[base4] = r0;
  *(float4*)&orow[base4 + 32] = r1;
}

// ---------------- launch ----------------
// Workspace layout (bytes):            offset        size
//   xb  (bf16 x,  16384x512)               0      16777216
//   hxb (bf16 hx, 16384x512)        16777216      16777216
//   Wib (bf16,  1536x512)           33554432       1572864
//   Whb (bf16,  1536x512)           35127296       1572864
//   xt  (bf16, 16384x1536, permuted) 36700160     50331648
//   ht  (bf16, 16384x1536, permuted) 87031808     50331648
extern "C" void kernel_launch(void* const* d_in, const int* in_sizes, int n_in,
                              void* d_out, int out_size, void* d_ws, size_t ws_size,
                              hipStream_t stream) {
  const float* x  = (const float*)d_in[0];
  const float* hx = (const float*)d_in[1];
  const float* Wi = (const float*)d_in[2];
  const float* bi = (const float*)d_in[3];
  const float* Wh = (const float*)d_in[4];
  const float* bh = (const float*)d_in[5];
  float* out = (float*)d_out;

  char* ws = (char*)d_ws;
  unsigned short* xb  = (unsigned short*)(ws);
  unsigned short* hxb = (unsigned short*)(ws + 16777216);
  unsigned short* Wib = (unsigned short*)(ws + 33554432);
  unsigned short* Whb = (unsigned short*)(ws + 35127296);
  unsigned short* xt  = (unsigned short*)(ws + 36700160);
  unsigned short* ht  = (unsigned short*)(ws + 87031808);

  cvt_all<<<1792, 256, 0, stream>>>(x, hx, Wi, Wh, xb, hxb, Wib, Whb);

  gemm_bf16<<<dim3(M_ROWS / 256, N_COLS / 128, 2), 256, 0, stream>>>(
      xb, hxb, Wib, Whb, bi, bh, xt, ht);

  finalize_kernel<<<M_ROWS / 4, 256, 0, stream>>>(xt, ht, hxb, out);
}